// Round 6
// baseline (230.864 us; speedup 1.0000x reference)
//
#include <hip/hip_runtime.h>
#include <hip/hip_bf16.h>
#include <hip/hip_cooperative_groups.h>

namespace cg = cooperative_groups;

#define NB 2
#define NQS 1024
#define NKS 1024
#define DD 512
#define HH 32
#define NKROW (NB * NKS)  // 2048 key rows; query rows follow in E
#define W1S 34            // LDS stride: conflict-free B-frag reads
#define NTILES (NB * (NQS / 32) * (NKS / 64))  // 1024

typedef __attribute__((ext_vector_type(8))) short bf16x8;
typedef __attribute__((ext_vector_type(4))) float f32x4;

static __device__ __forceinline__ float fexp2(float x) {
#if __has_builtin(__builtin_amdgcn_exp2f)
  return __builtin_amdgcn_exp2f(x);
#else
  float r; asm("v_exp_f32 %0, %1" : "=v"(r) : "v"(x)); return r;
#endif
}
static __device__ __forceinline__ float frcp(float x) {
#if __has_builtin(__builtin_amdgcn_rcpf)
  return __builtin_amdgcn_rcpf(x);
#else
  float r; asm("v_rcp_f32 %0, %1" : "=v"(r) : "v"(x)); return r;
#endif
}

union SH {  // phase-1 W1 tile and phase-2 Eq tile share LDS (34.8 KB static)
  __hip_bfloat16 w1l[DD * W1S];
  float eql[32 * HH];
};

// Fused: phase 1 writes E[row][h] = exp2(S*(row.W1col + bias)) (blocks 0..63,
// each = 64 rows, 4 waves x one 16-row MFMA tile, full K per wave, no reduce);
// device fence + grid.sync + fence; phase 2 = R4 pair-merge scoring, Eq via
// LDS (vector loads only -- scalar cache must not touch E mid-kernel).
__global__ __launch_bounds__(256, 4) void fused_scorer(
    const float* __restrict__ keys, const float* __restrict__ queries,
    const float* __restrict__ W1, const float* __restrict__ b1,
    const float* __restrict__ W2, const float* __restrict__ b2,
    float* __restrict__ E, float* __restrict__ out) {
  __shared__ SH sh;
  const float S = 2.8853900817779268f;  // 2*log2(e)
  const int tid = threadIdx.x;
  // ---------------- Phase 1: projection ----------------
  for (int c = blockIdx.x; c < 64; c += gridDim.x) {
    const bool isq = c >= 32;
    const int row0b = c * 64;
    const float* src = isq ? queries + (size_t)(row0b - NKROW) * DD
                           : keys + (size_t)row0b * DD;
    const float* w1 = W1 + (isq ? (size_t)DD * HH : 0);
#pragma unroll
    for (int s = 0; s < 16; ++s) {  // stage W1 half -> bf16 LDS stride-34
      const int f = tid + s * 256;
      float4 v = *(const float4*)(w1 + (size_t)f * 4);
      const int k = f >> 3, h0 = (f & 7) * 4;
      __hip_bfloat16* p = &sh.w1l[k * W1S + h0];
      p[0] = __float2bfloat16(v.x); p[1] = __float2bfloat16(v.y);
      p[2] = __float2bfloat16(v.z); p[3] = __float2bfloat16(v.w);
    }
    __syncthreads();
    const int l = tid & 63, w = tid >> 6;
    const int m = l & 15, kq = l >> 4;
    f32x4 acc0 = {0.f, 0.f, 0.f, 0.f}, acc1 = {0.f, 0.f, 0.f, 0.f};
    const float* arow = src + (size_t)(w * 16 + m) * DD + kq * 8;
    union Frag { bf16x8 v; __hip_bfloat16 e[8]; };
#pragma unroll
    for (int s = 0; s < 16; ++s) {
      float4 a0 = *(const float4*)(arow + s * 32);
      float4 a1 = *(const float4*)(arow + s * 32 + 4);
      Frag af, bf0, bf1;
      af.e[0] = __float2bfloat16(a0.x); af.e[1] = __float2bfloat16(a0.y);
      af.e[2] = __float2bfloat16(a0.z); af.e[3] = __float2bfloat16(a0.w);
      af.e[4] = __float2bfloat16(a1.x); af.e[5] = __float2bfloat16(a1.y);
      af.e[6] = __float2bfloat16(a1.z); af.e[7] = __float2bfloat16(a1.w);
      const __hip_bfloat16* bp = &sh.w1l[(s * 32 + kq * 8) * W1S + m];
#pragma unroll
      for (int j = 0; j < 8; ++j) {
        bf0.e[j] = bp[j * W1S];
        bf1.e[j] = bp[j * W1S + 16];
      }
      acc0 = __builtin_amdgcn_mfma_f32_16x16x32_bf16(af.v, bf0.v, acc0, 0, 0, 0);
      acc1 = __builtin_amdgcn_mfma_f32_16x16x32_bf16(af.v, bf1.v, acc1, 0, 0, 0);
    }
    float bias0 = isq ? b1[m] : 0.f, bias1 = isq ? b1[16 + m] : 0.f;
#pragma unroll
    for (int r = 0; r < 4; ++r) {  // C/D: col=lane&15, row=(lane>>4)*4+reg
      const int rr = row0b + w * 16 + kq * 4 + r;
      E[(size_t)rr * HH + m] = fexp2(S * (acc0[r] + bias0));
      E[(size_t)rr * HH + 16 + m] = fexp2(S * (acc1[r] + bias1));
    }
    __syncthreads();
  }
  __threadfence();          // agent-scope release: push E out of this XCD's L2
  cg::this_grid().sync();
  __threadfence();          // agent-scope acquire: invalidate stale L1/L2
  // ---------------- Phase 2: scoring (R4 pair-merge) ----------------
  for (int t = blockIdx.x; t < NTILES; t += gridDim.x) {
    const int kt = t & 15, qt = (t >> 4) & 31, b = t >> 9;
    const int k0 = kt * 64, q0 = qt * 32;
    const int kl = tid & 63, qg = tid >> 6;  // qg wave-uniform
    const float* ekp = E + (size_t)(b * NKS + k0 + kl) * HH;  // per-lane (vector)
    float ek[HH];
#pragma unroll
    for (int i = 0; i < 8; ++i) {
      float4 v = *(const float4*)(ekp + i * 4);
      ek[i * 4 + 0] = v.x; ek[i * 4 + 1] = v.y;
      ek[i * 4 + 2] = v.z; ek[i * 4 + 3] = v.w;
    }
    __syncthreads();  // LDS reuse guard (phase-1 w1l / previous tile)
    *(float4*)(sh.eql + tid * 4) =
        *(const float4*)(E + ((size_t)NKROW + (size_t)b * NQS + q0) * HH + tid * 4);
    __syncthreads();
    float c0 = b2[0];
    float w2v[HH];
#pragma unroll
    for (int h = 0; h < HH; ++h) { float ww = W2[h]; c0 += ww; w2v[h] = -2.f * ww; }
    float Aa[16], Bb[16], C01[16];
#pragma unroll
    for (int i = 0; i < 16; ++i) {
      Aa[i] = w2v[2 * i] * ek[2 * i + 1];
      Bb[i] = w2v[2 * i + 1] * ek[2 * i];
      C01[i] = w2v[2 * i] + w2v[2 * i + 1];
    }
    const float* eqrow = sh.eql + qg * 8 * HH;
    float* outp = out + ((size_t)b * NQS + q0 + qg * 8) * NKS + k0 + kl;
#pragma unroll 2
    for (int j = 0; j < 8; ++j) {
      const float* ej = eqrow + j * HH;  // LDS broadcast reads
      float acc0 = c0, acc1 = 0.f;
#pragma unroll
      for (int i2 = 0; i2 < 8; ++i2) {
        float4 ev = *(const float4*)(ej + i2 * 4);
        {
          const int i = 2 * i2;
          float da = fmaf(ek[2 * i], ev.x, 1.f);
          float db = fmaf(ek[2 * i + 1], ev.y, 1.f);
          float num = fmaf(Aa[i], ev.y, fmaf(Bb[i], ev.x, C01[i]));
          acc0 = fmaf(num, frcp(da * db), acc0);
        }
        {
          const int i = 2 * i2 + 1;
          float da = fmaf(ek[2 * i], ev.z, 1.f);
          float db = fmaf(ek[2 * i + 1], ev.w, 1.f);
          float num = fmaf(Aa[i], ev.w, fmaf(Bb[i], ev.z, C01[i]));
          acc1 = fmaf(num, frcp(da * db), acc1);
        }
      }
      outp[(size_t)j * NKS] = acc0 + acc1;
    }
  }
}

// ---------------- Fallback (R4 two-kernel path) ----------------
__global__ __launch_bounds__(256) void p1_proj_mfma(
    const float* __restrict__ keys, const float* __restrict__ queries,
    const float* __restrict__ W1, const float* __restrict__ b1,
    float* __restrict__ E) {
  __shared__ __hip_bfloat16 W1L[DD * W1S];
  __shared__ float red[4 * 2 * 64 * 4];
  const float S = 2.8853900817779268f;
  const int tid = threadIdx.x;
  const int row0 = blockIdx.x * 16;
  const bool isq = row0 >= NKROW;
  const float* src = isq ? queries + (size_t)(row0 - NKROW) * DD
                         : keys + (size_t)row0 * DD;
  const float* w1 = W1 + (isq ? (size_t)DD * HH : 0);
#pragma unroll
  for (int s = 0; s < 16; ++s) {
    const int f = tid + s * 256;
    float4 v = *(const float4*)(w1 + (size_t)f * 4);
    const int k = f >> 3, h0 = (f & 7) * 4;
    __hip_bfloat16* p = &W1L[k * W1S + h0];
    p[0] = __float2bfloat16(v.x); p[1] = __float2bfloat16(v.y);
    p[2] = __float2bfloat16(v.z); p[3] = __float2bfloat16(v.w);
  }
  __syncthreads();
  const int l = tid & 63, w = tid >> 6;
  const int m = l & 15, kq = l >> 4;
  f32x4 acc0 = {0.f, 0.f, 0.f, 0.f}, acc1 = {0.f, 0.f, 0.f, 0.f};
  const float* arow = src + (size_t)m * DD + w * 128 + kq * 8;
  union Frag { bf16x8 v; __hip_bfloat16 e[8]; };
#pragma unroll
  for (int s = 0; s < 4; ++s) {
    const int kb = w * 128 + s * 32;
    float4 a0 = *(const float4*)(arow + s * 32);
    float4 a1 = *(const float4*)(arow + s * 32 + 4);
    Frag af, bf0, bf1;
    af.e[0] = __float2bfloat16(a0.x); af.e[1] = __float2bfloat16(a0.y);
    af.e[2] = __float2bfloat16(a0.z); af.e[3] = __float2bfloat16(a0.w);
    af.e[4] = __float2bfloat16(a1.x); af.e[5] = __float2bfloat16(a1.y);
    af.e[6] = __float2bfloat16(a1.z); af.e[7] = __float2bfloat16(a1.w);
    const __hip_bfloat16* bp = &W1L[(kb + kq * 8) * W1S + m];
#pragma unroll
    for (int j = 0; j < 8; ++j) {
      bf0.e[j] = bp[j * W1S];
      bf1.e[j] = bp[j * W1S + 16];
    }
    acc0 = __builtin_amdgcn_mfma_f32_16x16x32_bf16(af.v, bf0.v, acc0, 0, 0, 0);
    acc1 = __builtin_amdgcn_mfma_f32_16x16x32_bf16(af.v, bf1.v, acc1, 0, 0, 0);
  }
  *(f32x4*)(&red[((w * 2 + 0) * 64 + l) * 4]) = acc0;
  *(f32x4*)(&red[((w * 2 + 1) * 64 + l) * 4]) = acc1;
  __syncthreads();
#pragma unroll
  for (int u = 0; u < 2; ++u) {
    const int o = tid + u * 256;
    const int rr = o >> 5, h = o & 31;
    const int tt = h >> 4, mm = h & 15;
    const int ll = ((rr >> 2) << 4) | mm, r = rr & 3;
    float sum = red[(0 + tt) * 256 + ll * 4 + r] + red[(2 + tt) * 256 + ll * 4 + r] +
                red[(4 + tt) * 256 + ll * 4 + r] + red[(6 + tt) * 256 + ll * 4 + r];
    if (isq) sum += b1[h];
    E[(size_t)(row0 + rr) * HH + h] = fexp2(S * sum);
  }
}

__global__ __launch_bounds__(256) void p2_score(
    const float* __restrict__ E, const float* __restrict__ W2,
    const float* __restrict__ b2, float* __restrict__ out) {
  const int tid = threadIdx.x;
  const int kl = tid & 63;
  const int qg = __builtin_amdgcn_readfirstlane(tid >> 6);
  const int k0 = blockIdx.x * 64, q0 = blockIdx.y * 32, b = blockIdx.z;
  const float* ekp = E + (size_t)(b * NKS + k0 + kl) * HH;
  float ek[HH];
#pragma unroll
  for (int i = 0; i < 8; ++i) {
    float4 v = *(const float4*)(ekp + i * 4);
    ek[i * 4 + 0] = v.x; ek[i * 4 + 1] = v.y;
    ek[i * 4 + 2] = v.z; ek[i * 4 + 3] = v.w;
  }
  float c0 = b2[0];
  float w2v[HH];
#pragma unroll
  for (int h = 0; h < HH; ++h) { float ww = W2[h]; c0 += ww; w2v[h] = -2.f * ww; }
  float Aa[16], Bb[16], C01[16];
#pragma unroll
  for (int i = 0; i < 16; ++i) {
    Aa[i] = w2v[2 * i] * ek[2 * i + 1];
    Bb[i] = w2v[2 * i + 1] * ek[2 * i];
    C01[i] = w2v[2 * i] + w2v[2 * i + 1];
  }
  const float* eqb = E + ((size_t)NKROW + (size_t)b * NQS + q0 + qg * 8) * HH;
  float* outp = out + ((size_t)b * NQS + q0 + qg * 8) * NKS + k0 + kl;
#pragma unroll 2
  for (int j = 0; j < 8; ++j) {
    const float* ej = eqb + (size_t)j * HH;
    float acc0 = c0, acc1 = 0.f;
#pragma unroll
    for (int i2 = 0; i2 < 8; ++i2) {
      float4 ev = *(const float4*)(ej + i2 * 4);
      {
        const int i = 2 * i2;
        float da = fmaf(ek[2 * i], ev.x, 1.f);
        float db = fmaf(ek[2 * i + 1], ev.y, 1.f);
        float num = fmaf(Aa[i], ev.y, fmaf(Bb[i], ev.x, C01[i]));
        acc0 = fmaf(num, frcp(da * db), acc0);
      }
      {
        const int i = 2 * i2 + 1;
        float da = fmaf(ek[2 * i], ev.z, 1.f);
        float db = fmaf(ek[2 * i + 1], ev.w, 1.f);
        float num = fmaf(Aa[i], ev.w, fmaf(Bb[i], ev.z, C01[i]));
        acc1 = fmaf(num, frcp(da * db), acc1);
      }
    }
    outp[(size_t)j * NKS] = acc0 + acc1;
  }
}

extern "C" void kernel_launch(void* const* d_in, const int* in_sizes, int n_in,
                              void* d_out, int out_size, void* d_ws, size_t ws_size,
                              hipStream_t stream) {
  const float* keys = (const float*)d_in[0];
  const float* queries = (const float*)d_in[1];
  const float* W1 = (const float*)d_in[2];
  const float* b1 = (const float*)d_in[3];
  const float* W2 = (const float*)d_in[4];
  const float* b2 = (const float*)d_in[5];
  float* out = (float*)d_out;
  float* E = (float*)d_ws;  // [4096][32] fp32 = 512 KB

  void* args[] = {&keys, &queries, &W1, &b1, &W2, &b2, &E, &out};
  hipError_t rc = hipLaunchCooperativeKernel(
      (void*)fused_scorer, dim3(NTILES), dim3(256), args, 0, stream);
  if (rc != hipSuccess) {  // fallback: proven R4 two-kernel path
    hipLaunchKernelGGL(p1_proj_mfma, dim3(256), dim3(256), 0, stream,
                       keys, queries, W1, b1, E);
    hipLaunchKernelGGL(p2_score, dim3(NKS / 64, NQS / 32, NB), dim3(256), 0, stream,
                       E, W2, b2, out);
  }
}

// Round 7
// 85.457 us; speedup vs baseline: 2.7015x; 2.7015x over previous
//
#include <hip/hip_runtime.h>
#include <hip/hip_bf16.h>

#define NB 2
#define NQS 1024
#define NKS 1024
#define DD 512
#define HH 32
#define NKROW (NB * NKS)  // 2048 key rows; query rows follow in E
#define W1S 34            // LDS stride: conflict-free B-frag reads

typedef __attribute__((ext_vector_type(8))) short bf16x8;
typedef __attribute__((ext_vector_type(4))) float f32x4;

static __device__ __forceinline__ float fexp2(float x) {
#if __has_builtin(__builtin_amdgcn_exp2f)
  return __builtin_amdgcn_exp2f(x);
#else
  float r; asm("v_exp_f32 %0, %1" : "=v"(r) : "v"(x)); return r;
#endif
}
static __device__ __forceinline__ float frcp(float x) {
#if __has_builtin(__builtin_amdgcn_rcpf)
  return __builtin_amdgcn_rcpf(x);
#else
  float r; asm("v_rcp_f32 %0, %1" : "=v"(r) : "v"(x)); return r;
#endif
}

// Phase 1 (MFMA, split-K x4): E[row][h] = exp2(S*(row.W1col + (isq? b1 : 0))).
// 256 blocks x 256 thr. Block = 16 rows; wave w owns K-range [w*128, w*128+128).
// W1 half staged to LDS bf16 stride-34; split-K reduce via LDS; exp2 epilogue.
__global__ __launch_bounds__(256) void p1_proj_mfma(
    const float* __restrict__ keys, const float* __restrict__ queries,
    const float* __restrict__ W1, const float* __restrict__ b1,
    float* __restrict__ E) {
  __shared__ __hip_bfloat16 W1L[DD * W1S];
  __shared__ float red[4 * 2 * 64 * 4];  // [wave][ntile][lane][reg]
  const float S = 2.8853900817779268f;   // 2*log2(e)
  const int tid = threadIdx.x;
  const int row0 = blockIdx.x * 16;
  const bool isq = row0 >= NKROW;
  const float* src = isq ? queries + (size_t)(row0 - NKROW) * DD
                         : keys + (size_t)row0 * DD;
  const float* w1 = W1 + (isq ? (size_t)DD * HH : 0);
#pragma unroll
  for (int s = 0; s < 16; ++s) {
    const int f = tid + s * 256;
    float4 v = *(const float4*)(w1 + (size_t)f * 4);
    const int k = f >> 3, h0 = (f & 7) * 4;
    __hip_bfloat16* p = &W1L[k * W1S + h0];
    p[0] = __float2bfloat16(v.x); p[1] = __float2bfloat16(v.y);
    p[2] = __float2bfloat16(v.z); p[3] = __float2bfloat16(v.w);
  }
  __syncthreads();
  const int l = tid & 63, w = tid >> 6;
  const int m = l & 15, kq = l >> 4;
  f32x4 acc0 = {0.f, 0.f, 0.f, 0.f}, acc1 = {0.f, 0.f, 0.f, 0.f};
  const float* arow = src + (size_t)m * DD + w * 128 + kq * 8;
  union Frag { bf16x8 v; __hip_bfloat16 e[8]; };
#pragma unroll
  for (int s = 0; s < 4; ++s) {
    const int kb = w * 128 + s * 32;
    float4 a0 = *(const float4*)(arow + s * 32);
    float4 a1 = *(const float4*)(arow + s * 32 + 4);
    Frag af, bf0, bf1;
    af.e[0] = __float2bfloat16(a0.x); af.e[1] = __float2bfloat16(a0.y);
    af.e[2] = __float2bfloat16(a0.z); af.e[3] = __float2bfloat16(a0.w);
    af.e[4] = __float2bfloat16(a1.x); af.e[5] = __float2bfloat16(a1.y);
    af.e[6] = __float2bfloat16(a1.z); af.e[7] = __float2bfloat16(a1.w);
    const __hip_bfloat16* bp = &W1L[(kb + kq * 8) * W1S + m];
#pragma unroll
    for (int j = 0; j < 8; ++j) {
      bf0.e[j] = bp[j * W1S];
      bf1.e[j] = bp[j * W1S + 16];
    }
    acc0 = __builtin_amdgcn_mfma_f32_16x16x32_bf16(af.v, bf0.v, acc0, 0, 0, 0);
    acc1 = __builtin_amdgcn_mfma_f32_16x16x32_bf16(af.v, bf1.v, acc1, 0, 0, 0);
  }
  *(f32x4*)(&red[((w * 2 + 0) * 64 + l) * 4]) = acc0;
  *(f32x4*)(&red[((w * 2 + 1) * 64 + l) * 4]) = acc1;
  __syncthreads();
#pragma unroll
  for (int u = 0; u < 2; ++u) {
    const int o = tid + u * 256;
    const int rr = o >> 5, h = o & 31;
    const int tt = h >> 4, mm = h & 15;
    const int ll = ((rr >> 2) << 4) | mm, r = rr & 3;
    float sum = red[(0 + tt) * 256 + ll * 4 + r] + red[(2 + tt) * 256 + ll * 4 + r] +
                red[(4 + tt) * 256 + ll * 4 + r] + red[(6 + tt) * 256 + ll * 4 + r];
    if (isq) sum += b1[h];
    E[(size_t)(row0 + rr) * HH + h] = fexp2(S * sum);
  }
}

// Phase 2 v4 (occupancy-first): per pair of h-terms,
//   w0/da + w1/db = (w0*db + w1*da) * rcp(da*db),  da = 1+ek0*eq0, db = 1+ek1*eq1.
// Numerator uses only UNIFORM w0,w1 (SGPRs) + da/db -> no per-lane Aa/Bb/C01
// arrays -> ~50 VGPR -> 8 waves/SIMD. Tile 64k x 16q, grid 2048 (8 blocks/CU).
__global__ __launch_bounds__(256, 8) void p2_score(
    const float* __restrict__ E, const float* __restrict__ W2,
    const float* __restrict__ b2, float* __restrict__ out) {
  const int tid = threadIdx.x;
  const int kl = tid & 63;
  const int qg = __builtin_amdgcn_readfirstlane(tid >> 6);  // wave-uniform
  const int k0 = blockIdx.x * 64, q0 = blockIdx.y * 16, b = blockIdx.z;
  const float* ekp = E + (size_t)(b * NKS + k0 + kl) * HH;
  float ek[HH];
#pragma unroll
  for (int i = 0; i < 8; ++i) {
    float4 v = *(const float4*)(ekp + i * 4);
    ek[i * 4 + 0] = v.x; ek[i * 4 + 1] = v.y;
    ek[i * 4 + 2] = v.z; ek[i * 4 + 3] = v.w;
  }
  float c0 = b2[0];
  float w2v[HH];  // uniform -> SGPRs
#pragma unroll
  for (int h = 0; h < HH; ++h) { float ww = W2[h]; c0 += ww; w2v[h] = -2.f * ww; }
  const float* eqb = E + ((size_t)NKROW + (size_t)b * NQS + q0 + qg * 4) * HH;
  float* outp = out + ((size_t)b * NQS + q0 + qg * 4) * NKS + k0 + kl;
#pragma unroll 2
  for (int j = 0; j < 4; ++j) {
    const float* ej = eqb + (size_t)j * HH;  // uniform -> s_load
    float acc0 = c0, acc1 = 0.f;
#pragma unroll
    for (int i2 = 0; i2 < 8; ++i2) {
      float4 ev = *(const float4*)(ej + i2 * 4);
      {
        const int i = 2 * i2;  // pair (h=2i, 2i+1)
        float da = fmaf(ek[2 * i], ev.x, 1.f);
        float db = fmaf(ek[2 * i + 1], ev.y, 1.f);
        float num = fmaf(w2v[2 * i], db, w2v[2 * i + 1] * da);
        acc0 = fmaf(num, frcp(da * db), acc0);
      }
      {
        const int i = 2 * i2 + 1;
        float da = fmaf(ek[2 * i], ev.z, 1.f);
        float db = fmaf(ek[2 * i + 1], ev.w, 1.f);
        float num = fmaf(w2v[2 * i], db, w2v[2 * i + 1] * da);
        acc1 = fmaf(num, frcp(da * db), acc1);
      }
    }
    outp[(size_t)j * NKS] = acc0 + acc1;
  }
}

extern "C" void kernel_launch(void* const* d_in, const int* in_sizes, int n_in,
                              void* d_out, int out_size, void* d_ws, size_t ws_size,
                              hipStream_t stream) {
  const float* keys = (const float*)d_in[0];
  const float* queries = (const float*)d_in[1];
  const float* W1 = (const float*)d_in[2];
  const float* b1 = (const float*)d_in[3];
  const float* W2 = (const float*)d_in[4];
  const float* b2 = (const float*)d_in[5];
  float* out = (float*)d_out;
  float* ws = (float*)d_ws;  // E: [4096][32] fp32 = 512 KB

  hipLaunchKernelGGL(p1_proj_mfma, dim3(256), dim3(256), 0, stream,
                     keys, queries, W1, b1, ws);
  hipLaunchKernelGGL(p2_score, dim3(NKS / 64, NQS / 16, NB), dim3(256), 0, stream,
                     ws, W2, b2, out);
}

// Round 9
// 22.093 us; speedup vs baseline: 10.4498x; 3.8681x over previous
//
#include <hip/hip_runtime.h>
#include <hip/hip_bf16.h>

#define NB 2
#define NQS 1024
#define NKS 1024
#define DD 512
#define HH 32
#define NKROW (NB * NKS)  // 2048 key rows; query rows follow in E
#define W1S 34            // LDS stride: conflict-free B-frag reads

typedef __attribute__((ext_vector_type(8))) short bf16x8;
typedef __attribute__((ext_vector_type(4))) float f32x4;

static __device__ __forceinline__ float fexp2(float x) {
#if __has_builtin(__builtin_amdgcn_exp2f)
  return __builtin_amdgcn_exp2f(x);
#else
  float r; asm("v_exp_f32 %0, %1" : "=v"(r) : "v"(x)); return r;
#endif
}
static __device__ __forceinline__ float frcp(float x) {
#if __has_builtin(__builtin_amdgcn_rcpf)
  return __builtin_amdgcn_rcpf(x);
#else
  float r; asm("v_rcp_f32 %0, %1" : "=v"(r) : "v"(x)); return r;
#endif
}
// readfirstlane that preserves float bits (the builtin takes/returns int!)
static __device__ __forceinline__ float rfl_f32(float x) {
  return __int_as_float(__builtin_amdgcn_readfirstlane(__float_as_int(x)));
}

// Phase 1 (MFMA, split-K x4): E[row][h] = exp2(S*(row.W1col + (isq? b1 : 0))).
// 256 blocks x 256 thr. Block = 16 rows; wave w owns K-range [w*128, w*128+128).
// W1 half staged to LDS bf16 stride-34; split-K reduce via LDS; exp2 epilogue.
__global__ __launch_bounds__(256) void p1_proj_mfma(
    const float* __restrict__ keys, const float* __restrict__ queries,
    const float* __restrict__ W1, const float* __restrict__ b1,
    float* __restrict__ E) {
  __shared__ __hip_bfloat16 W1L[DD * W1S];
  __shared__ float red[4 * 2 * 64 * 4];  // [wave][ntile][lane][reg]
  const float S = 2.8853900817779268f;   // 2*log2(e)
  const int tid = threadIdx.x;
  const int row0 = blockIdx.x * 16;
  const bool isq = row0 >= NKROW;
  const float* src = isq ? queries + (size_t)(row0 - NKROW) * DD
                         : keys + (size_t)row0 * DD;
  const float* w1 = W1 + (isq ? (size_t)DD * HH : 0);
#pragma unroll
  for (int s = 0; s < 16; ++s) {
    const int f = tid + s * 256;
    float4 v = *(const float4*)(w1 + (size_t)f * 4);
    const int k = f >> 3, h0 = (f & 7) * 4;
    __hip_bfloat16* p = &W1L[k * W1S + h0];
    p[0] = __float2bfloat16(v.x); p[1] = __float2bfloat16(v.y);
    p[2] = __float2bfloat16(v.z); p[3] = __float2bfloat16(v.w);
  }
  __syncthreads();
  const int l = tid & 63, w = tid >> 6;
  const int m = l & 15, kq = l >> 4;
  f32x4 acc0 = {0.f, 0.f, 0.f, 0.f}, acc1 = {0.f, 0.f, 0.f, 0.f};
  const float* arow = src + (size_t)m * DD + w * 128 + kq * 8;
  union Frag { bf16x8 v; __hip_bfloat16 e[8]; };
#pragma unroll
  for (int s = 0; s < 4; ++s) {
    const int kb = w * 128 + s * 32;
    float4 a0 = *(const float4*)(arow + s * 32);
    float4 a1 = *(const float4*)(arow + s * 32 + 4);
    Frag af, bf0, bf1;
    af.e[0] = __float2bfloat16(a0.x); af.e[1] = __float2bfloat16(a0.y);
    af.e[2] = __float2bfloat16(a0.z); af.e[3] = __float2bfloat16(a0.w);
    af.e[4] = __float2bfloat16(a1.x); af.e[5] = __float2bfloat16(a1.y);
    af.e[6] = __float2bfloat16(a1.z); af.e[7] = __float2bfloat16(a1.w);
    const __hip_bfloat16* bp = &W1L[(kb + kq * 8) * W1S + m];
#pragma unroll
    for (int j = 0; j < 8; ++j) {
      bf0.e[j] = bp[j * W1S];
      bf1.e[j] = bp[j * W1S + 16];
    }
    acc0 = __builtin_amdgcn_mfma_f32_16x16x32_bf16(af.v, bf0.v, acc0, 0, 0, 0);
    acc1 = __builtin_amdgcn_mfma_f32_16x16x32_bf16(af.v, bf1.v, acc1, 0, 0, 0);
  }
  *(f32x4*)(&red[((w * 2 + 0) * 64 + l) * 4]) = acc0;
  *(f32x4*)(&red[((w * 2 + 1) * 64 + l) * 4]) = acc1;
  __syncthreads();
#pragma unroll
  for (int u = 0; u < 2; ++u) {
    const int o = tid + u * 256;
    const int rr = o >> 5, h = o & 31;
    const int tt = h >> 4, mm = h & 15;
    const int ll = ((rr >> 2) << 4) | mm, r = rr & 3;
    float sum = red[(0 + tt) * 256 + ll * 4 + r] + red[(2 + tt) * 256 + ll * 4 + r] +
                red[(4 + tt) * 256 + ll * 4 + r] + red[(6 + tt) * 256 + ll * 4 + r];
    if (isq) sum += b1[h];
    E[(size_t)(row0 + rr) * HH + h] = fexp2(S * sum);
  }
}

// Phase 2 v6 (register-lean, fixed): logit = c0 - 2 * sum_h w_h * rcp(1+ek*eq),
// pair-merged: w0*rcp(da)+w1*rcp(db) = (w0*db+w1*da)*rcp(da*db).
// Raw W2 values readfirstlane'd (bit-cast) -> true SGPRs, ZERO arithmetic on
// them (SALU has no float ops; any scaling would demote to VGPR). -2 applied
// once per output. h in two halves of 16 -> only ek[16] live -> ~44 VGPR.
__global__ __launch_bounds__(256, 4) void p2_score(
    const float* __restrict__ E, const float* __restrict__ W2,
    const float* __restrict__ b2, float* __restrict__ out) {
  const int tid = threadIdx.x;
  const int kl = tid & 63;
  const int qg = __builtin_amdgcn_readfirstlane(tid >> 6);  // wave-uniform
  const int k0 = blockIdx.x * 64, q0 = blockIdx.y * 32, b = blockIdx.z;
  float w2v[HH];  // SGPR-resident raw weights
  float c0 = rfl_f32(b2[0]);
#pragma unroll
  for (int h = 0; h < HH; ++h) {
    w2v[h] = rfl_f32(W2[h]);
    c0 += w2v[h];
  }
  const float* ekp = E + (size_t)(b * NKS + k0 + kl) * HH;
  float acc[8];
#pragma unroll
  for (int j = 0; j < 8; ++j) acc[j] = c0;
#pragma unroll
  for (int half = 0; half < 2; ++half) {
    float ek[16];
#pragma unroll
    for (int i = 0; i < 4; ++i) {
      float4 v = *(const float4*)(ekp + half * 16 + i * 4);
      ek[i * 4 + 0] = v.x; ek[i * 4 + 1] = v.y;
      ek[i * 4 + 2] = v.z; ek[i * 4 + 3] = v.w;
    }
    const float* eqb =
        E + ((size_t)NKROW + (size_t)b * NQS + q0 + qg * 8) * HH + half * 16;
#pragma unroll
    for (int j = 0; j < 8; ++j) {
      const float* ej = eqb + (size_t)j * HH;  // uniform -> s_load
      float a0 = 0.f, a1 = 0.f;
#pragma unroll
      for (int i2 = 0; i2 < 4; ++i2) {
        float4 ev = *(const float4*)(ej + i2 * 4);
        const int hb = half * 16 + i2 * 4;
        {
          float da = fmaf(ek[i2 * 4 + 0], ev.x, 1.f);
          float db = fmaf(ek[i2 * 4 + 1], ev.y, 1.f);
          float num = fmaf(w2v[hb + 0], db, w2v[hb + 1] * da);
          a0 = fmaf(num, frcp(da * db), a0);
        }
        {
          float da = fmaf(ek[i2 * 4 + 2], ev.z, 1.f);
          float db = fmaf(ek[i2 * 4 + 3], ev.w, 1.f);
          float num = fmaf(w2v[hb + 2], db, w2v[hb + 3] * da);
          a1 = fmaf(num, frcp(da * db), a1);
        }
      }
      acc[j] = fmaf(-2.f, a0 + a1, acc[j]);
    }
  }
  float* outp = out + ((size_t)b * NQS + q0 + qg * 8) * NKS + k0 + kl;
#pragma unroll
  for (int j = 0; j < 8; ++j) outp[(size_t)j * NKS] = acc[j];
}

extern "C" void kernel_launch(void* const* d_in, const int* in_sizes, int n_in,
                              void* d_out, int out_size, void* d_ws, size_t ws_size,
                              hipStream_t stream) {
  const float* keys = (const float*)d_in[0];
  const float* queries = (const float*)d_in[1];
  const float* W1 = (const float*)d_in[2];
  const float* b1 = (const float*)d_in[3];
  const float* W2 = (const float*)d_in[4];
  const float* b2 = (const float*)d_in[5];
  float* out = (float*)d_out;
  float* ws = (float*)d_ws;  // E: [4096][32] fp32 = 512 KB

  hipLaunchKernelGGL(p1_proj_mfma, dim3(256), dim3(256), 0, stream,
                     keys, queries, W1, b1, ws);
  hipLaunchKernelGGL(p2_score, dim3(NKS / 64, NQS / 32, NB), dim3(256), 0, stream,
                     ws, W2, b2, out);
}